// Round 19
// baseline (111.527 us; speedup 1.0000x reference)
//
#include <hip/hip_runtime.h>
#include <stdint.h>

typedef __attribute__((ext_vector_type(8))) __bf16 bf16x8;
typedef __attribute__((ext_vector_type(8))) unsigned short u16x8;
typedef __attribute__((ext_vector_type(4))) float f32x4;
typedef __attribute__((ext_vector_type(4))) unsigned short u16x4;

typedef __attribute__((address_space(1))) unsigned int as1_uint;
typedef __attribute__((address_space(3))) unsigned int as3_uint;

__device__ __forceinline__ unsigned short f2bf(float f) {
  unsigned int u = __float_as_uint(f);
  u += 0x7fffu + ((u >> 16) & 1u);
  return (unsigned short)(u >> 16);
}

__device__ __forceinline__ void gload_lds16(const void* g, void* l) {
  __builtin_amdgcn_global_load_lds((as1_uint*)(uintptr_t)g, (as3_uint*)(uintptr_t)l,
                                   16, 0, 0);
}

// ---- fused fp32->bf16 converts: 4 elementwise inputs + o_proj transpose ----
// blocks [0,10240): elementwise (x, qp, kp, vp); [10240,11264): transpose op->opT
__global__ __launch_bounds__(256)
void cvt_fused(const float* __restrict__ x, const float* __restrict__ qp,
               const float* __restrict__ kp, const float* __restrict__ vp,
               const float* __restrict__ op,
               unsigned short* __restrict__ xb, unsigned short* __restrict__ qpb,
               unsigned short* __restrict__ kpb, unsigned short* __restrict__ vpb,
               unsigned short* __restrict__ opT) {
  __shared__ unsigned short t[64][72];
  const int b = blockIdx.x;
  if (b < 10240) {
    const float* in;
    unsigned short* out;
    int base;
    if (b < 4096)      { in = x;  out = xb;  base = b; }
    else if (b < 8192) { in = qp; out = qpb; base = b - 4096; }
    else if (b < 9216) { in = kp; out = kpb; base = b - 8192; }
    else               { in = vp; out = vpb; base = b - 9216; }
    const int i = base * 256 + threadIdx.x;
    float4 v = ((const float4*)in)[i];
    u16x4 o;
    o[0] = f2bf(v.x); o[1] = f2bf(v.y); o[2] = f2bf(v.z); o[3] = f2bf(v.w);
    ((u16x4*)out)[i] = o;
    return;
  }
  // transpose-convert: op [2048][2048] -> opT [2048][2048]
  const int tb = b - 10240;
  const int tj = (tb & 31) * 64;
  const int ti = (tb >> 5) * 64;
  const int r  = threadIdx.x >> 4;
  const int c4 = (threadIdx.x & 15) * 4;
#pragma unroll
  for (int i = 0; i < 4; ++i) {
    int row = r + i * 16;
    float4 v = *(const float4*)&op[(size_t)(ti + row) * 2048 + tj + c4];
    t[row][c4]     = f2bf(v.x);
    t[row][c4 + 1] = f2bf(v.y);
    t[row][c4 + 2] = f2bf(v.z);
    t[row][c4 + 3] = f2bf(v.w);
  }
  __syncthreads();
#pragma unroll
  for (int i = 0; i < 4; ++i) {
    int orow = r + i * 16;
    u16x4 o;
    o[0] = t[c4][orow]; o[1] = t[c4 + 1][orow];
    o[2] = t[c4 + 2][orow]; o[3] = t[c4 + 3][orow];
    *(u16x4*)&opT[(size_t)(tj + orow) * 2048 + ti + c4] = o;
  }
}

// ---------------- NT GEMM body: C[M][N] = A[M][K] * B[N][K]^T, bf16 MFMA --------
template <int BN, bool OUT_BF16>
__device__ __forceinline__
void gemm_body(const unsigned short* __restrict__ A,
               const unsigned short* __restrict__ B,
               void* __restrict__ Cout, int N, int K, float alpha,
               int bx, int by, unsigned short* lA, unsigned short* lB) {
  constexpr int NF  = BN / 32;   // 16-col fragments per wave
  constexpr int ASZ = 64 * 64;
  constexpr int BSZ = BN * 64;
  const int tid  = threadIdx.x;
  const int lane = tid & 63;
  const int w    = tid >> 6;
  const int wr   = (w >> 1) * 32;
  const int wc   = (w & 1) * (BN / 2);
  const long brow = (long)by * 64;
  const long bcol = (long)bx * BN;
  const int lr = lane & 15;
  const int lq = lane >> 4;

  const int row0 = tid >> 3;
  const int lc0  = (tid & 7) ^ (row0 & 7);

  f32x4 acc[2][NF] = {};

  const unsigned short* gA = A + (brow + row0) * (long)K + lc0 * 8;
  const unsigned short* gB = B + (bcol + row0) * (long)K + lc0 * 8;

#define G_STAGE(buf, k0)                                                          \
  {                                                                               \
    gload_lds16(gA + (k0),           lA + (buf) * ASZ + tid * 8);                 \
    gload_lds16(gA + 32l * K + (k0), lA + (buf) * ASZ + 2048 + tid * 8);          \
    _Pragma("unroll")                                                             \
    for (int g = 0; g < NF; ++g)                                                  \
      gload_lds16(gB + g * 32l * K + (k0), lB + (buf) * BSZ + g * 2048 + tid * 8);\
  }

  G_STAGE(0, 0);
  __syncthreads();

  for (int k0 = 0; k0 < K; k0 += 64) {
    const int cur = (k0 >> 6) & 1;
    if (k0 + 64 < K) G_STAGE(cur ^ 1, k0 + 64);  // prefetch rides through compute
#pragma unroll
    for (int kk = 0; kk < 2; ++kk) {
      const int j = kk * 4 + lq;
      const int ra0 = wr + lr, ra1 = wr + 16 + lr;
      bf16x8 a0 = *(const bf16x8*)&lA[cur * ASZ + ra0 * 64 + ((j ^ (ra0 & 7)) << 3)];
      bf16x8 a1 = *(const bf16x8*)&lA[cur * ASZ + ra1 * 64 + ((j ^ (ra1 & 7)) << 3)];
      bf16x8 b[NF];
#pragma unroll
      for (int n = 0; n < NF; ++n) {
        const int rb = wc + n * 16 + lr;
        b[n] = *(const bf16x8*)&lB[cur * BSZ + rb * 64 + ((j ^ (rb & 7)) << 3)];
      }
#pragma unroll
      for (int n = 0; n < NF; ++n) {
        acc[0][n] = __builtin_amdgcn_mfma_f32_16x16x32_bf16(a0, b[n], acc[0][n], 0, 0, 0);
        acc[1][n] = __builtin_amdgcn_mfma_f32_16x16x32_bf16(a1, b[n], acc[1][n], 0, 0, 0);
      }
    }
    __syncthreads();
  }
#undef G_STAGE

  const int orow = (int)brow + wr + lq * 4;
  const int ocol = (int)bcol + wc + lr;
#pragma unroll
  for (int m = 0; m < 2; ++m)
#pragma unroll
    for (int n = 0; n < NF; ++n)
#pragma unroll
      for (int r = 0; r < 4; ++r) {
        size_t row = (size_t)(orow + m * 16 + r);
        size_t col = (size_t)(ocol + n * 16);
        float v = acc[m][n][r] * alpha;
        if (OUT_BF16)
          ((unsigned short*)Cout)[row * N + col] = f2bf(v);
        else
          ((float*)Cout)[row * N + col] = v;
      }
}

// o-proj GEMM with T1 XCD-swizzle: grid (16,32) = 512 blocks = 8 x 64.
template <int BN, bool OUT_BF16>
__global__ __launch_bounds__(256)
void gemm_nt(const unsigned short* __restrict__ A,
             const unsigned short* __restrict__ B,
             void* __restrict__ Cout, int N, int K, float alpha) {
  __shared__ unsigned short lA[2 * 64 * 64];
  __shared__ unsigned short lB[2 * BN * 64];
  const int flat  = (int)blockIdx.x + (int)gridDim.x * (int)blockIdx.y;
  const int total = (int)(gridDim.x * gridDim.y);
  const int cpx   = total >> 3;              // total is a multiple of 8
  const int swz   = (flat & 7) * cpx + (flat >> 3);
  const int bx    = swz % (int)gridDim.x;
  const int by    = swz / (int)gridDim.x;
  gemm_body<BN, OUT_BF16>(A, B, Cout, N, K, alpha, bx, by, lA, lB);
}

// Fused Q+K+V projections, one dispatch, 768 blocks (= 8 x 96), T1 XCD-swizzle
//   [0,512)   Q = xb @ qpb^T (alpha=log2e/8), 16x * 32y
//   [512,640) K = xb @ kpb^T,                  4x * 32y
//   [640,768) Vt = vpb @ xb^T,                16x *  8y
__global__ __launch_bounds__(256)
void gemm_proj(const unsigned short* __restrict__ xb,
               const unsigned short* __restrict__ qpb,
               const unsigned short* __restrict__ kpb,
               const unsigned short* __restrict__ vpb,
               unsigned short* __restrict__ Qb, unsigned short* __restrict__ Kbf,
               unsigned short* __restrict__ Vtb) {
  __shared__ unsigned short lA[2 * 64 * 64];
  __shared__ unsigned short lB[2 * 128 * 64];
  const int raw = blockIdx.x;
  const int bid = (raw & 7) * 96 + (raw >> 3);   // bijective on [0,768)
  const unsigned short *A, *B;
  unsigned short* C;
  int N, bx, by;
  float alpha;
  if (bid < 512) {
    A = xb;  B = qpb; C = Qb;  N = 2048; alpha = 0.125f * 1.44269504088896f;
    bx = bid & 15; by = bid >> 4;
  } else if (bid < 640) {
    int b = bid - 512;
    A = xb;  B = kpb; C = Kbf; N = 512;  alpha = 1.0f;
    bx = b & 3; by = b >> 2;
  } else {
    int b = bid - 640;
    A = vpb; B = xb;  C = Vtb; N = 2048; alpha = 1.0f;
    bx = b & 15; by = b >> 4;
  }
  gemm_body<128, true>(A, B, C, N, 2048, alpha, bx, by, lA, lB);
}

// ---------------- causal GQA flash attention ----------------
// R19 = R18 (zero-shuffle in-register P) + LAGGED PV (T15 analog):
// per tile t: QK(t) -> add PV(t-1) [pending reg-P, V from lV[(t-1)%3]] ->
// softmax(t) (mask/defer/rescale) -> pack P(t) into pending frags.
// Algebra: oacc and P(t-1) are both at scale mr(t-1) until the tile-t rescale,
// so adding PV(t-1) BEFORE the rescale is exact; l needs no lag.
// V is 3-buffered (writer of t+1 targets (t+2)%3 == (t-1)%3 AFTER the end-of-t
// barrier that also closes the pending reads -> no conflict); K stays 2-buf.
// LDS = 2x8K (K) + 3x8K (V) = 40960 B -> 4 blocks/CU unchanged.
__global__ __launch_bounds__(256, 4)
void attn64(const unsigned short* __restrict__ Q,
            const unsigned short* __restrict__ Kb,
            const unsigned short* __restrict__ Vt,
            unsigned short* __restrict__ ctx) {
  constexpr int T = 2048, DQ = 2048, DKV = 512, DH = 64;
  const int h    = blockIdx.x;
  const int hkv  = h >> 2;
  const int ya   = blockIdx.y >> 3;
  const int yb   = blockIdx.y & 7;
  const int qi   = (ya == 0) ? yb : (ya == 1) ? 15 - yb : (ya == 2) ? 16 + yb : 31 - yb;
  const int tid  = threadIdx.x;
  const int lane = tid & 63;
  const int lr   = lane & 15;
  const int lq   = lane >> 4;   // 0..3
  const int lk   = lq * 8;
  const int sw   = lr & 7;      // row-derived swizzle key for fragment reads

  __shared__ unsigned short lK[2][64 * 64];
  __shared__ unsigned short lV[3][64 * 64];

  const int row0 = tid >> 3;                 // LDS position row 0..31 (+32)
  const int lc0  = (tid & 7) ^ (row0 & 7);   // XOR involution chunk
  // sigma^-1 for K: global k row stored at position row0 (+32 for g=1)
  const int kperm = 8 * ((row0 >> 2) & 3) + 4 * ((row0 >> 4) & 1) + (row0 & 3);

#define STAGE_K(bufidx, kv0)                                                         \
  {                                                                                  \
    gload_lds16(Kb + (size_t)((kv0) + kperm) * DKV + hkv * DH + lc0 * 8,             \
                &lK[bufidx][tid * 8]);                                               \
    gload_lds16(Kb + (size_t)((kv0) + kperm + 32) * DKV + hkv * DH + lc0 * 8,        \
                &lK[bufidx][2048 + tid * 8]);                                        \
  }
#define STAGE_V(bufidx, kv0)                                                         \
  {                                                                                  \
    gload_lds16(Vt + (size_t)(hkv * DH + row0) * T + (kv0) + lc0 * 8,                \
                &lV[bufidx][tid * 8]);                                               \
    gload_lds16(Vt + (size_t)(hkv * DH + row0 + 32) * T + (kv0) + lc0 * 8,           \
                &lV[bufidx][2048 + tid * 8]);                                        \
  }

  const int q0b = qi * 64;
  const int qw  = q0b + (tid >> 6) * 16;   // wave w owns q-rows qw..qw+15

  bf16x8 qf0 = *(const bf16x8*)&Q[(size_t)(qw + lr) * DQ + h * DH + lk];
  bf16x8 qf1 = *(const bf16x8*)&Q[(size_t)(qw + lr) * DQ + h * DH + 32 + lk];

  f32x4 oacc[4] = {};
  float l  = 0.f;
  float mr = -3.0e38f;
  u16x8 pk0p = {}, pk1p = {};   // pending P fragments (tile t-1)

  const int nt = qi + 1;
  STAGE_K(0, 0);
  STAGE_V(0, 0);
  __syncthreads();  // drains vmcnt(0): buf0 ready

  int vw = 1;   // V write target for prefetch at tile t = (t+1)%3
  int vr = 2;   // V read (pending) at tile t = (t-1)%3; valid from t=1 on

  for (int t = 0; t < nt; ++t) {
    const int kv0 = t * 64;
    const int kcur = t & 1;
    if (t + 1 < nt) {
      STAGE_K(kcur ^ 1, kv0 + 64);
      STAGE_V(vw, kv0 + 64);
    }

    // ---- swapped QK^T: s[n] = K-tile(n) x Q ----
    f32x4 s[4];
    __builtin_amdgcn_s_setprio(1);
#pragma unroll
    for (int n = 0; n < 4; ++n) {
      const int krow = n * 16 + lr;   // LDS position row
      bf16x8 kf0 = *(const bf16x8*)&lK[kcur][krow * 64 + ((lq ^ sw) << 3)];
      bf16x8 kf1 = *(const bf16x8*)&lK[kcur][krow * 64 + (((4 + lq) ^ sw) << 3)];
      f32x4 acc = {};
      acc = __builtin_amdgcn_mfma_f32_16x16x32_bf16(kf0, qf0, acc, 0, 0, 0);
      acc = __builtin_amdgcn_mfma_f32_16x16x32_bf16(kf1, qf1, acc, 0, 0, 0);
      s[n] = acc;
    }
    // ---- lagged PV(t-1): pending reg-P x lV[(t-1)%3]; independent MFMA chain ----
    if (t > 0) {
      bf16x8 pf0 = *(bf16x8*)&pk0p;
      bf16x8 pf1 = *(bf16x8*)&pk1p;
#pragma unroll
      for (int m = 0; m < 4; ++m) {
        const int vrow = m * 16 + lr;
        bf16x8 vf0 = *(const bf16x8*)&lV[vr][vrow * 64 + ((lq ^ sw) << 3)];
        bf16x8 vf1 = *(const bf16x8*)&lV[vr][vrow * 64 + (((4 + lq) ^ sw) << 3)];
        oacc[m] = __builtin_amdgcn_mfma_f32_16x16x32_bf16(pf0, vf0, oacc[m], 0, 0, 0);
        oacc[m] = __builtin_amdgcn_mfma_f32_16x16x32_bf16(pf1, vf1, oacc[m], 0, 0, 0);
      }
    }
    __builtin_amdgcn_s_setprio(0);
    // lane (lr,lq) holds S[k_global = kv0+32(n>>1)+8lq+4(n&1)+r][q = qw+lr]

    // ---- causal mask: only the diagonal tile needs it ----
    if (t == qi) {
      const int kb = kv0 + 8 * lq;
      const int qg = qw + lr;
#pragma unroll
      for (int n = 0; n < 4; ++n) {
        const int kn = kb + 32 * (n >> 1) + 4 * (n & 1);
#pragma unroll
        for (int r = 0; r < 4; ++r)
          if (kn + r > qg) s[n][r] = -3.0e38f;
      }
    }

    // ---- online softmax with defer-max (THR = 8 log2-units); q=lr per lane ----
    float lml = fmaxf(fmaxf(fmaxf(s[0][0], s[0][1]), fmaxf(s[0][2], s[0][3])),
                      fmaxf(fmaxf(s[1][0], s[1][1]), fmaxf(s[1][2], s[1][3])));
    lml = fmaxf(lml, fmaxf(fmaxf(s[2][0], s[2][1]), fmaxf(s[2][2], s[2][3])));
    lml = fmaxf(lml, fmaxf(fmaxf(s[3][0], s[3][1]), fmaxf(s[3][2], s[3][3])));
    const bool defer = __all(lml <= mr + 8.f);
    if (!defer) {
      float rm = lml;
      rm = fmaxf(rm, __shfl_xor(rm, 16));
      rm = fmaxf(rm, __shfl_xor(rm, 32));
      float mnew = fmaxf(mr, rm);
      float sc   = __builtin_amdgcn_exp2f(mr - mnew);
      mr = mnew;
      l *= sc;
      float sc4[4];
#pragma unroll
      for (int r = 0; r < 4; ++r) sc4[r] = __shfl(sc, (lq << 2) + r);
#pragma unroll
      for (int m = 0; m < 4; ++m)
#pragma unroll
        for (int r = 0; r < 4; ++r) oacc[m][r] *= sc4[r];
    }

    // ---- P = exp2(s - mr): trunc-pack into pending PV A-fragments ----
    float ps = 0.f;
#pragma unroll
    for (int n = 0; n < 4; ++n)
#pragma unroll
      for (int r = 0; r < 4; ++r) {
        float p = __builtin_amdgcn_exp2f(s[n][r] - mr);
        unsigned int u = __float_as_uint(p);
        ps += __uint_as_float(u & 0xFFFF0000u);   // sum exactly what PV consumes
        const int j = ((n & 1) << 2) + r;         // k offset within 8-slice
        if (n < 2) pk0p[j] = (unsigned short)(u >> 16);
        else       pk1p[j] = (unsigned short)(u >> 16);
      }
    ps += __shfl_xor(ps, 16);
    ps += __shfl_xor(ps, 32);
    l += ps;

    // one barrier per tile: prefetch landed; pending-V reads closed before its
    // overwrite (issued at t+1); K[cur] free for t+1's prefetch target at t+2
    __syncthreads();
    vr = vw == 0 ? 2 : vw - 1;   // (t)%3 becomes pending index next iteration
    vw = vw == 2 ? 0 : vw + 1;
  }

  // ---- epilogue: final pending PV(nt-1) from lV[(nt-1)%3] ----
  {
    bf16x8 pf0 = *(bf16x8*)&pk0p;
    bf16x8 pf1 = *(bf16x8*)&pk1p;
#pragma unroll
    for (int m = 0; m < 4; ++m) {
      const int vrow = m * 16 + lr;
      bf16x8 vf0 = *(const bf16x8*)&lV[vr][vrow * 64 + ((lq ^ sw) << 3)];
      bf16x8 vf1 = *(const bf16x8*)&lV[vr][vrow * 64 + (((4 + lq) ^ sw) << 3)];
      oacc[m] = __builtin_amdgcn_mfma_f32_16x16x32_bf16(pf0, vf0, oacc[m], 0, 0, 0);
      oacc[m] = __builtin_amdgcn_mfma_f32_16x16x32_bf16(pf1, vf1, oacc[m], 0, 0, 0);
    }
  }

  float inv[4];
#pragma unroll
  for (int r = 0; r < 4; ++r)
    inv[r] = 1.f / __shfl(l, (lq << 2) + r);   // l lives at lane lr == q-row
#pragma unroll
  for (int m = 0; m < 4; ++m)
#pragma unroll
    for (int r = 0; r < 4; ++r) {
      int qrow = qw + (lq << 2) + r;
      ctx[(size_t)qrow * DQ + h * DH + m * 16 + lr] = f2bf(oacc[m][r] * inv[r]);
    }
#undef STAGE_K
#undef STAGE_V
}

extern "C" void kernel_launch(void* const* d_in, const int* in_sizes, int n_in,
                              void* d_out, int out_size, void* d_ws, size_t ws_size,
                              hipStream_t stream) {
  const float* x  = (const float*)d_in[0];
  const float* qp = (const float*)d_in[1];
  const float* kp = (const float*)d_in[2];
  const float* vp = (const float*)d_in[3];
  const float* op = (const float*)d_in[4];

  char* ws = (char*)d_ws;
  const size_t MB = 1024 * 1024;
  unsigned short* xb   = (unsigned short*)(ws + 0 * MB);   // [2048][2048]
  unsigned short* qpb  = (unsigned short*)(ws + 8 * MB);   // [2048][2048]
  unsigned short* kpb  = (unsigned short*)(ws + 16 * MB);  // [512][2048]
  unsigned short* vpb  = (unsigned short*)(ws + 18 * MB);  // [512][2048]
  unsigned short* opT  = (unsigned short*)(ws + 20 * MB);  // [2048][2048] = o_proj^T
  unsigned short* Qb   = (unsigned short*)(ws + 28 * MB);  // [2048][2048]
  unsigned short* Kbf  = (unsigned short*)(ws + 36 * MB);  // [2048][512]
  unsigned short* Vtb  = (unsigned short*)(ws + 38 * MB);  // [512][2048]
  unsigned short* ctxb = (unsigned short*)(ws + 40 * MB);  // [2048][2048]

  // fp32 -> bf16 (4 elementwise inputs + o_proj transpose), ONE dispatch
  cvt_fused<<<11264, 256, 0, stream>>>(x, qp, kp, vp, op, xb, qpb, kpb, vpb, opT);

  // Fused Q+K+V projections (Q scaled by log2(e)/8), XCD-swizzled
  gemm_proj<<<768, 256, 0, stream>>>(xb, qpb, kpb, vpb, Qb, Kbf, Vtb);

  // causal GQA attention: x = head (XCD-pinned K/V), y -> balanced qi bijection
  attn64<<<dim3(32, 32), 256, 0, stream>>>(Qb, Kbf, Vtb, ctxb);

  // out = ctx @ o_proj  (via opT, NT form), fp32 epilogue, XCD-swizzled
  gemm_nt<128, false><<<dim3(16, 32), 256, 0, stream>>>(ctxb, opT, d_out, 2048, 2048, 1.0f);
}

// Round 20
// 110.636 us; speedup vs baseline: 1.0080x; 1.0080x over previous
//
#include <hip/hip_runtime.h>
#include <stdint.h>

typedef __attribute__((ext_vector_type(8))) __bf16 bf16x8;
typedef __attribute__((ext_vector_type(8))) unsigned short u16x8;
typedef __attribute__((ext_vector_type(4))) float f32x4;
typedef __attribute__((ext_vector_type(4))) unsigned short u16x4;

typedef __attribute__((address_space(1))) unsigned int as1_uint;
typedef __attribute__((address_space(3))) unsigned int as3_uint;

__device__ __forceinline__ unsigned short f2bf(float f) {
  unsigned int u = __float_as_uint(f);
  u += 0x7fffu + ((u >> 16) & 1u);
  return (unsigned short)(u >> 16);
}

__device__ __forceinline__ void gload_lds16(const void* g, void* l) {
  __builtin_amdgcn_global_load_lds((as1_uint*)(uintptr_t)g, (as3_uint*)(uintptr_t)l,
                                   16, 0, 0);
}

// ---- fused fp32->bf16 converts: 4 elementwise inputs + o_proj transpose ----
// blocks [0,10240): elementwise (x, qp, kp, vp); [10240,11264): transpose op->opT
__global__ __launch_bounds__(256)
void cvt_fused(const float* __restrict__ x, const float* __restrict__ qp,
               const float* __restrict__ kp, const float* __restrict__ vp,
               const float* __restrict__ op,
               unsigned short* __restrict__ xb, unsigned short* __restrict__ qpb,
               unsigned short* __restrict__ kpb, unsigned short* __restrict__ vpb,
               unsigned short* __restrict__ opT) {
  __shared__ unsigned short t[64][72];
  const int b = blockIdx.x;
  if (b < 10240) {
    const float* in;
    unsigned short* out;
    int base;
    if (b < 4096)      { in = x;  out = xb;  base = b; }
    else if (b < 8192) { in = qp; out = qpb; base = b - 4096; }
    else if (b < 9216) { in = kp; out = kpb; base = b - 8192; }
    else               { in = vp; out = vpb; base = b - 9216; }
    const int i = base * 256 + threadIdx.x;
    float4 v = ((const float4*)in)[i];
    u16x4 o;
    o[0] = f2bf(v.x); o[1] = f2bf(v.y); o[2] = f2bf(v.z); o[3] = f2bf(v.w);
    ((u16x4*)out)[i] = o;
    return;
  }
  // transpose-convert: op [2048][2048] -> opT [2048][2048]
  const int tb = b - 10240;
  const int tj = (tb & 31) * 64;
  const int ti = (tb >> 5) * 64;
  const int r  = threadIdx.x >> 4;
  const int c4 = (threadIdx.x & 15) * 4;
#pragma unroll
  for (int i = 0; i < 4; ++i) {
    int row = r + i * 16;
    float4 v = *(const float4*)&op[(size_t)(ti + row) * 2048 + tj + c4];
    t[row][c4]     = f2bf(v.x);
    t[row][c4 + 1] = f2bf(v.y);
    t[row][c4 + 2] = f2bf(v.z);
    t[row][c4 + 3] = f2bf(v.w);
  }
  __syncthreads();
#pragma unroll
  for (int i = 0; i < 4; ++i) {
    int orow = r + i * 16;
    u16x4 o;
    o[0] = t[c4][orow]; o[1] = t[c4 + 1][orow];
    o[2] = t[c4 + 2][orow]; o[3] = t[c4 + 3][orow];
    *(u16x4*)&opT[(size_t)(tj + orow) * 2048 + ti + c4] = o;
  }
}

// ---------------- NT GEMM body: C[M][N] = A[M][K] * B[N][K]^T, bf16 MFMA --------
template <int BN, bool OUT_BF16>
__device__ __forceinline__
void gemm_body(const unsigned short* __restrict__ A,
               const unsigned short* __restrict__ B,
               void* __restrict__ Cout, int N, int K, float alpha,
               int bx, int by, unsigned short* lA, unsigned short* lB) {
  constexpr int NF  = BN / 32;   // 16-col fragments per wave
  constexpr int ASZ = 64 * 64;
  constexpr int BSZ = BN * 64;
  const int tid  = threadIdx.x;
  const int lane = tid & 63;
  const int w    = tid >> 6;
  const int wr   = (w >> 1) * 32;
  const int wc   = (w & 1) * (BN / 2);
  const long brow = (long)by * 64;
  const long bcol = (long)bx * BN;
  const int lr = lane & 15;
  const int lq = lane >> 4;

  const int row0 = tid >> 3;
  const int lc0  = (tid & 7) ^ (row0 & 7);

  f32x4 acc[2][NF] = {};

  const unsigned short* gA = A + (brow + row0) * (long)K + lc0 * 8;
  const unsigned short* gB = B + (bcol + row0) * (long)K + lc0 * 8;

#define G_STAGE(buf, k0)                                                          \
  {                                                                               \
    gload_lds16(gA + (k0),           lA + (buf) * ASZ + tid * 8);                 \
    gload_lds16(gA + 32l * K + (k0), lA + (buf) * ASZ + 2048 + tid * 8);          \
    _Pragma("unroll")                                                             \
    for (int g = 0; g < NF; ++g)                                                  \
      gload_lds16(gB + g * 32l * K + (k0), lB + (buf) * BSZ + g * 2048 + tid * 8);\
  }

  G_STAGE(0, 0);
  __syncthreads();

  for (int k0 = 0; k0 < K; k0 += 64) {
    const int cur = (k0 >> 6) & 1;
    if (k0 + 64 < K) G_STAGE(cur ^ 1, k0 + 64);  // prefetch rides through compute
#pragma unroll
    for (int kk = 0; kk < 2; ++kk) {
      const int j = kk * 4 + lq;
      const int ra0 = wr + lr, ra1 = wr + 16 + lr;
      bf16x8 a0 = *(const bf16x8*)&lA[cur * ASZ + ra0 * 64 + ((j ^ (ra0 & 7)) << 3)];
      bf16x8 a1 = *(const bf16x8*)&lA[cur * ASZ + ra1 * 64 + ((j ^ (ra1 & 7)) << 3)];
      bf16x8 b[NF];
#pragma unroll
      for (int n = 0; n < NF; ++n) {
        const int rb = wc + n * 16 + lr;
        b[n] = *(const bf16x8*)&lB[cur * BSZ + rb * 64 + ((j ^ (rb & 7)) << 3)];
      }
#pragma unroll
      for (int n = 0; n < NF; ++n) {
        acc[0][n] = __builtin_amdgcn_mfma_f32_16x16x32_bf16(a0, b[n], acc[0][n], 0, 0, 0);
        acc[1][n] = __builtin_amdgcn_mfma_f32_16x16x32_bf16(a1, b[n], acc[1][n], 0, 0, 0);
      }
    }
    __syncthreads();
  }
#undef G_STAGE

  const int orow = (int)brow + wr + lq * 4;
  const int ocol = (int)bcol + wc + lr;
#pragma unroll
  for (int m = 0; m < 2; ++m)
#pragma unroll
    for (int n = 0; n < NF; ++n)
#pragma unroll
      for (int r = 0; r < 4; ++r) {
        size_t row = (size_t)(orow + m * 16 + r);
        size_t col = (size_t)(ocol + n * 16);
        float v = acc[m][n][r] * alpha;
        if (OUT_BF16)
          ((unsigned short*)Cout)[row * N + col] = f2bf(v);
        else
          ((float*)Cout)[row * N + col] = v;
      }
}

// o-proj GEMM with T1 XCD-swizzle: grid (16,32) = 512 blocks = 8 x 64.
template <int BN, bool OUT_BF16>
__global__ __launch_bounds__(256)
void gemm_nt(const unsigned short* __restrict__ A,
             const unsigned short* __restrict__ B,
             void* __restrict__ Cout, int N, int K, float alpha) {
  __shared__ unsigned short lA[2 * 64 * 64];
  __shared__ unsigned short lB[2 * BN * 64];
  const int flat  = (int)blockIdx.x + (int)gridDim.x * (int)blockIdx.y;
  const int total = (int)(gridDim.x * gridDim.y);
  const int cpx   = total >> 3;              // total is a multiple of 8
  const int swz   = (flat & 7) * cpx + (flat >> 3);
  const int bx    = swz % (int)gridDim.x;
  const int by    = swz / (int)gridDim.x;
  gemm_body<BN, OUT_BF16>(A, B, Cout, N, K, alpha, bx, by, lA, lB);
}

// Fused Q+K+V projections, one dispatch, 768 blocks (= 8 x 96), T1 XCD-swizzle
//   [0,512)   Q = xb @ qpb^T (alpha=log2e/8), 16x * 32y
//   [512,640) K = xb @ kpb^T,                  4x * 32y
//   [640,768) Vt = vpb @ xb^T,                16x *  8y
__global__ __launch_bounds__(256)
void gemm_proj(const unsigned short* __restrict__ xb,
               const unsigned short* __restrict__ qpb,
               const unsigned short* __restrict__ kpb,
               const unsigned short* __restrict__ vpb,
               unsigned short* __restrict__ Qb, unsigned short* __restrict__ Kbf,
               unsigned short* __restrict__ Vtb) {
  __shared__ unsigned short lA[2 * 64 * 64];
  __shared__ unsigned short lB[2 * 128 * 64];
  const int raw = blockIdx.x;
  const int bid = (raw & 7) * 96 + (raw >> 3);   // bijective on [0,768)
  const unsigned short *A, *B;
  unsigned short* C;
  int N, bx, by;
  float alpha;
  if (bid < 512) {
    A = xb;  B = qpb; C = Qb;  N = 2048; alpha = 0.125f * 1.44269504088896f;
    bx = bid & 15; by = bid >> 4;
  } else if (bid < 640) {
    int b = bid - 512;
    A = xb;  B = kpb; C = Kbf; N = 512;  alpha = 1.0f;
    bx = b & 3; by = b >> 2;
  } else {
    int b = bid - 640;
    A = vpb; B = xb;  C = Vtb; N = 2048; alpha = 1.0f;
    bx = b & 15; by = b >> 4;
  }
  gemm_body<128, true>(A, B, C, N, 2048, alpha, bx, by, lA, lB);
}

// ---------------- causal GQA flash attention ----------------
// R20 = R18-exact (best measured: attn 43.5 us, total 111.0). Zero-shuffle
// in-register P: swapped QK^T (s = mfma(K,Q)) + permuted K staging so the
// lane's 16 exp'd scores pack directly into PV's A-fragments — no P LDS
// array, no lgkmcnt, no cross-lane moves. Row state (mr,l) scalar per lane
// (q=lr); reduce = 2 shfl_xor; rescale broadcast only on !defer; l sums the
// truncation-reconstructed p (num/denom cancellation). R19's lagged-PV was
// neutral-to-negative (inter-block TLP already covers the softmax bubble)
// and is NOT included. LDS 32768 B -> 4 blocks/CU, 16 waves/CU.
__global__ __launch_bounds__(256, 4)
void attn64(const unsigned short* __restrict__ Q,
            const unsigned short* __restrict__ Kb,
            const unsigned short* __restrict__ Vt,
            unsigned short* __restrict__ ctx) {
  constexpr int T = 2048, DQ = 2048, DKV = 512, DH = 64;
  const int h    = blockIdx.x;
  const int hkv  = h >> 2;
  const int ya   = blockIdx.y >> 3;
  const int yb   = blockIdx.y & 7;
  const int qi   = (ya == 0) ? yb : (ya == 1) ? 15 - yb : (ya == 2) ? 16 + yb : 31 - yb;
  const int tid  = threadIdx.x;
  const int lane = tid & 63;
  const int lr   = lane & 15;
  const int lq   = lane >> 4;   // 0..3
  const int lk   = lq * 8;
  const int sw   = lr & 7;      // row-derived swizzle key for fragment reads

  __shared__ unsigned short lK[2][64 * 64];
  __shared__ unsigned short lV[2][64 * 64];

  const int row0 = tid >> 3;                 // LDS position row 0..31 (+32)
  const int lc0  = (tid & 7) ^ (row0 & 7);   // XOR involution chunk
  // sigma^-1 for K: global k row stored at position row0 (+32 for g=1)
  const int kperm = 8 * ((row0 >> 2) & 3) + 4 * ((row0 >> 4) & 1) + (row0 & 3);

#define STAGE_KV(bufidx, kv0)                                                        \
  {                                                                                  \
    gload_lds16(Kb + (size_t)((kv0) + kperm) * DKV + hkv * DH + lc0 * 8,             \
                &lK[bufidx][tid * 8]);                                               \
    gload_lds16(Kb + (size_t)((kv0) + kperm + 32) * DKV + hkv * DH + lc0 * 8,        \
                &lK[bufidx][2048 + tid * 8]);                                        \
    gload_lds16(Vt + (size_t)(hkv * DH + row0) * T + (kv0) + lc0 * 8,                \
                &lV[bufidx][tid * 8]);                                               \
    gload_lds16(Vt + (size_t)(hkv * DH + row0 + 32) * T + (kv0) + lc0 * 8,           \
                &lV[bufidx][2048 + tid * 8]);                                        \
  }

  const int q0b = qi * 64;
  const int qw  = q0b + (tid >> 6) * 16;   // wave w owns q-rows qw..qw+15

  bf16x8 qf0 = *(const bf16x8*)&Q[(size_t)(qw + lr) * DQ + h * DH + lk];
  bf16x8 qf1 = *(const bf16x8*)&Q[(size_t)(qw + lr) * DQ + h * DH + 32 + lk];

  f32x4 oacc[4] = {};
  float l  = 0.f;
  float mr = -3.0e38f;

  const int nt = qi + 1;
  STAGE_KV(0, 0);
  __syncthreads();  // drains vmcnt(0): buf0 ready

  for (int t = 0; t < nt; ++t) {
    const int kv0 = t * 64;
    const int cur = t & 1;
    if (t + 1 < nt) STAGE_KV(cur ^ 1, kv0 + 64);  // prefetch rides through compute

    // ---- swapped QK^T: s[n] = K-tile(n) x Q; identical LDS reads to R17 ----
    f32x4 s[4];
    __builtin_amdgcn_s_setprio(1);
#pragma unroll
    for (int n = 0; n < 4; ++n) {
      const int krow = n * 16 + lr;   // LDS position row
      bf16x8 kf0 = *(const bf16x8*)&lK[cur][krow * 64 + ((lq ^ sw) << 3)];
      bf16x8 kf1 = *(const bf16x8*)&lK[cur][krow * 64 + (((4 + lq) ^ sw) << 3)];
      f32x4 acc = {};
      acc = __builtin_amdgcn_mfma_f32_16x16x32_bf16(kf0, qf0, acc, 0, 0, 0);
      acc = __builtin_amdgcn_mfma_f32_16x16x32_bf16(kf1, qf1, acc, 0, 0, 0);
      s[n] = acc;
    }
    __builtin_amdgcn_s_setprio(0);
    // lane (lr,lq) now holds S[k_global = kv0+32(n>>1)+8lq+4(n&1)+r][q = qw+lr]

    // ---- causal mask: only the diagonal tile needs it ----
    if (t == qi) {
      const int kb = kv0 + 8 * lq;
      const int qg = qw + lr;
#pragma unroll
      for (int n = 0; n < 4; ++n) {
        const int kn = kb + 32 * (n >> 1) + 4 * (n & 1);
#pragma unroll
        for (int r = 0; r < 4; ++r)
          if (kn + r > qg) s[n][r] = -3.0e38f;
      }
    }

    // ---- online softmax with defer-max (THR = 8 log2-units); q=lr per lane ----
    float lml = fmaxf(fmaxf(fmaxf(s[0][0], s[0][1]), fmaxf(s[0][2], s[0][3])),
                      fmaxf(fmaxf(s[1][0], s[1][1]), fmaxf(s[1][2], s[1][3])));
    lml = fmaxf(lml, fmaxf(fmaxf(s[2][0], s[2][1]), fmaxf(s[2][2], s[2][3])));
    lml = fmaxf(lml, fmaxf(fmaxf(s[3][0], s[3][1]), fmaxf(s[3][2], s[3][3])));
    const bool defer = __all(lml <= mr + 8.f);
    if (!defer) {
      float rm = lml;
      rm = fmaxf(rm, __shfl_xor(rm, 16));
      rm = fmaxf(rm, __shfl_xor(rm, 32));
      float mnew = fmaxf(mr, rm);
      float sc   = __builtin_amdgcn_exp2f(mr - mnew);
      mr = mnew;
      l *= sc;
      float sc4[4];
#pragma unroll
      for (int r = 0; r < 4; ++r) sc4[r] = __shfl(sc, (lq << 2) + r);
#pragma unroll
      for (int m = 0; m < 4; ++m)
#pragma unroll
        for (int r = 0; r < 4; ++r) oacc[m][r] *= sc4[r];
    }

    // ---- P = exp2(s - mr): trunc-pack straight into PV A-fragments ----
    u16x8 pk0, pk1;
    float ps = 0.f;
#pragma unroll
    for (int n = 0; n < 4; ++n)
#pragma unroll
      for (int r = 0; r < 4; ++r) {
        float p = __builtin_amdgcn_exp2f(s[n][r] - mr);
        unsigned int u = __float_as_uint(p);
        ps += __uint_as_float(u & 0xFFFF0000u);   // sum exactly what PV consumes
        const int j = ((n & 1) << 2) + r;         // k offset within 8-slice
        if (n < 2) pk0[j] = (unsigned short)(u >> 16);
        else       pk1[j] = (unsigned short)(u >> 16);
      }
    ps += __shfl_xor(ps, 16);
    ps += __shfl_xor(ps, 32);
    l += ps;
    bf16x8 pf0 = *(bf16x8*)&pk0;   // k = 8lq..8lq+7
    bf16x8 pf1 = *(bf16x8*)&pk1;   // k = 32+8lq..+7

    // ---- PV from registers + LDS V (swizzled reads, unchanged) ----
    __builtin_amdgcn_s_setprio(1);
#pragma unroll
    for (int ks = 0; ks < 2; ++ks) {
      bf16x8 pf = ks ? pf1 : pf0;
#pragma unroll
      for (int m = 0; m < 4; ++m) {
        const int vrow = m * 16 + lr;
        bf16x8 vf = *(const bf16x8*)&lV[cur][vrow * 64 + (((ks * 4 + lq) ^ sw) << 3)];
        oacc[m] = __builtin_amdgcn_mfma_f32_16x16x32_bf16(pf, vf, oacc[m], 0, 0, 0);
      }
    }
    __builtin_amdgcn_s_setprio(0);

    // one barrier per tile: prefetch landed + all waves done with buf[cur]
    __syncthreads();
  }

  float inv[4];
#pragma unroll
  for (int r = 0; r < 4; ++r)
    inv[r] = 1.f / __shfl(l, (lq << 2) + r);   // l lives at lane lr == q-row
#pragma unroll
  for (int m = 0; m < 4; ++m)
#pragma unroll
    for (int r = 0; r < 4; ++r) {
      int qrow = qw + (lq << 2) + r;
      ctx[(size_t)qrow * DQ + h * DH + m * 16 + lr] = f2bf(oacc[m][r] * inv[r]);
    }
#undef STAGE_KV
}

extern "C" void kernel_launch(void* const* d_in, const int* in_sizes, int n_in,
                              void* d_out, int out_size, void* d_ws, size_t ws_size,
                              hipStream_t stream) {
  const float* x  = (const float*)d_in[0];
  const float* qp = (const float*)d_in[1];
  const float* kp = (const float*)d_in[2];
  const float* vp = (const float*)d_in[3];
  const float* op = (const float*)d_in[4];

  char* ws = (char*)d_ws;
  const size_t MB = 1024 * 1024;
  unsigned short* xb   = (unsigned short*)(ws + 0 * MB);   // [2048][2048]
  unsigned short* qpb  = (unsigned short*)(ws + 8 * MB);   // [2048][2048]
  unsigned short* kpb  = (unsigned short*)(ws + 16 * MB);  // [512][2048]
  unsigned short* vpb  = (unsigned short*)(ws + 18 * MB);  // [512][2048]
  unsigned short* opT  = (unsigned short*)(ws + 20 * MB);  // [2048][2048] = o_proj^T
  unsigned short* Qb   = (unsigned short*)(ws + 28 * MB);  // [2048][2048]
  unsigned short* Kbf  = (unsigned short*)(ws + 36 * MB);  // [2048][512]
  unsigned short* Vtb  = (unsigned short*)(ws + 38 * MB);  // [512][2048]
  unsigned short* ctxb = (unsigned short*)(ws + 40 * MB);  // [2048][2048]

  // fp32 -> bf16 (4 elementwise inputs + o_proj transpose), ONE dispatch
  cvt_fused<<<11264, 256, 0, stream>>>(x, qp, kp, vp, op, xb, qpb, kpb, vpb, opT);

  // Fused Q+K+V projections (Q scaled by log2(e)/8), XCD-swizzled
  gemm_proj<<<768, 256, 0, stream>>>(xb, qpb, kpb, vpb, Qb, Kbf, Vtb);

  // causal GQA attention: x = head (XCD-pinned K/V), y -> balanced qi bijection
  attn64<<<dim3(32, 32), 256, 0, stream>>>(Qb, Kbf, Vtb, ctxb);

  // out = ctx @ o_proj  (via opT, NT form), fp32 epilogue, XCD-swizzled
  gemm_nt<128, false><<<dim3(16, 32), 256, 0, stream>>>(ctxb, opT, d_out, 2048, 2048, 1.0f);
}